// Round 1
// baseline (962.121 us; speedup 1.0000x reference)
//
#include <hip/hip_runtime.h>
#include <math.h>

#define HID    256
#define H4     64            // HID / 4 (float4 lanes per row)
#define NPG    512           // nodes per graph (harness-fixed)
#define EPS_F  1e-6f

// ---------------- Kernel 1: per-graph feature statistics ----------------
// One block per graph. The block streams its graph's 512 KB fully
// contiguously: 256 threads x float4 = 4 KB (4 rows) per iteration.
// Thread t owns feature quad f4 = t&63 at row-phase p = t>>6, so the
// per-feature column sums need only a 4-way LDS reduction at the end.
__global__ __launch_bounds__(256, 4)
void stats_kernel(const float* __restrict__ x,
                  const int*   __restrict__ bl,
                  const float* __restrict__ w,
                  const float* __restrict__ bias,
                  const float* __restrict__ ms,
                  float*       __restrict__ aA,   // [B][HID]  a = w * rstd
                  float*       __restrict__ cA)   // [B][HID]  c = b - mu * a
{
    const int g  = blockIdx.x;
    const int t  = threadIdx.x;
    const int f4 = t & (H4 - 1);
    const int p  = t >> 6;                     // 0..3 row phase

    const float4* __restrict__ x4 =
        reinterpret_cast<const float4*>(x) +
        (size_t)g * NPG * H4 + (size_t)p * H4 + f4;

    float4 s1 = make_float4(0.f, 0.f, 0.f, 0.f);
    float4 s2 = make_float4(0.f, 0.f, 0.f, 0.f);
#pragma unroll 8
    for (int i = 0; i < NPG / 4; ++i) {
        const float4 v = x4[(size_t)i * 4 * H4];
        s1.x += v.x; s1.y += v.y; s1.z += v.z; s1.w += v.w;
        s2.x = fmaf(v.x, v.x, s2.x);
        s2.y = fmaf(v.y, v.y, s2.y);
        s2.z = fmaf(v.z, v.z, s2.z);
        s2.w = fmaf(v.w, v.w, s2.w);
    }

    __shared__ float4 sh1[4][H4];
    __shared__ float4 sh2[4][H4];
    sh1[p][f4] = s1;
    sh2[p][f4] = s2;
    __syncthreads();

    if (t < H4) {
        float4 S1 = sh1[0][t];
        float4 S2 = sh2[0][t];
#pragma unroll
        for (int q = 1; q < 4; ++q) {
            const float4 a1 = sh1[q][t];
            const float4 a2 = sh2[q][t];
            S1.x += a1.x; S1.y += a1.y; S1.z += a1.z; S1.w += a1.w;
            S2.x += a2.x; S2.y += a2.y; S2.z += a2.z; S2.w += a2.w;
        }
        const float inv = 1.0f / (float)bl[g];
        const int   f   = t * 4;
        const float4 wv = *reinterpret_cast<const float4*>(w    + f);
        const float4 bv = *reinterpret_cast<const float4*>(bias + f);
        const float4 mv = *reinterpret_cast<const float4*>(ms   + f);
        float4 av, cv;
        {
            const float m   = S1.x * inv;
            const float var = S2.x * inv - m * m * mv.x * (2.0f - mv.x);
            const float a   = wv.x * rsqrtf(var + EPS_F);
            av.x = a;  cv.x = bv.x - m * mv.x * a;
        }
        {
            const float m   = S1.y * inv;
            const float var = S2.y * inv - m * m * mv.y * (2.0f - mv.y);
            const float a   = wv.y * rsqrtf(var + EPS_F);
            av.y = a;  cv.y = bv.y - m * mv.y * a;
        }
        {
            const float m   = S1.z * inv;
            const float var = S2.z * inv - m * m * mv.z * (2.0f - mv.z);
            const float a   = wv.z * rsqrtf(var + EPS_F);
            av.z = a;  cv.z = bv.z - m * mv.z * a;
        }
        {
            const float m   = S1.w * inv;
            const float var = S2.w * inv - m * m * mv.w * (2.0f - mv.w);
            const float a   = wv.w * rsqrtf(var + EPS_F);
            av.w = a;  cv.w = bv.w - m * mv.w * a;
        }
        reinterpret_cast<float4*>(aA)[(size_t)g * H4 + t] = av;
        reinterpret_cast<float4*>(cA)[(size_t)g * H4 + t] = cv;
    }
}

// ---------------- Kernel 2: streaming normalize ----------------
// One block per 64 contiguous rows (64 divides NPG, so a block never
// crosses a graph boundary). Pure sequential read + write; one fmaf
// per element with per-block cached (a, c) params.
#define RPB 64               // rows per block
__global__ __launch_bounds__(256, 4)
void norm_kernel(const float* __restrict__ x,
                 const float* __restrict__ aA,
                 const float* __restrict__ cA,
                 float*       __restrict__ out)
{
    const int t  = threadIdx.x;
    const int f4 = t & (H4 - 1);
    const int p  = t >> 6;                       // 0..3 row phase
    const size_t row0 = (size_t)blockIdx.x * RPB;
    const int g  = (int)(row0 / NPG);

    const float4 a = reinterpret_cast<const float4*>(aA)[(size_t)g * H4 + f4];
    const float4 c = reinterpret_cast<const float4*>(cA)[(size_t)g * H4 + f4];

    const float4* __restrict__ xi =
        reinterpret_cast<const float4*>(x)   + (row0 + p) * H4 + f4;
    float4* __restrict__ oi =
        reinterpret_cast<float4*>(out)       + (row0 + p) * H4 + f4;

#pragma unroll
    for (int i = 0; i < RPB / 4; ++i) {
        const float4 v = xi[(size_t)i * 4 * H4];
        float4 o;
        o.x = fmaf(v.x, a.x, c.x);
        o.y = fmaf(v.y, a.y, c.y);
        o.z = fmaf(v.z, a.z, c.z);
        o.w = fmaf(v.w, a.w, c.w);
        oi[(size_t)i * 4 * H4] = o;
    }
}

extern "C" void kernel_launch(void* const* d_in, const int* in_sizes, int n_in,
                              void* d_out, int out_size, void* d_ws, size_t ws_size,
                              hipStream_t stream) {
    const float* x    = (const float*)d_in[0];
    const int*   bl   = (const int*)d_in[1];
    const float* w    = (const float*)d_in[2];
    const float* bias = (const float*)d_in[3];
    const float* ms   = (const float*)d_in[4];
    float*       out  = (float*)d_out;

    const int B = in_sizes[1];                 // 1024 graphs
    float* aA = (float*)d_ws;                  // [B][HID]
    float* cA = aA + (size_t)B * HID;          // [B][HID]  (2 MB total scratch)

    stats_kernel<<<B, 256, 0, stream>>>(x, bl, w, bias, ms, aA, cA);

    const int n_rows   = B * NPG;              // 524288
    const int n_blocks = n_rows / RPB;         // 8192
    norm_kernel<<<n_blocks, 256, 0, stream>>>(x, aA, cA, out);
}